// Round 8
// baseline (1531.772 us; speedup 1.0000x reference)
//
#include <hip/hip_runtime.h>
#include <hip/hip_bf16.h>

typedef __hip_bfloat16 bf16;
typedef __bf16 bf16x8 __attribute__((ext_vector_type(8)));
typedef float  f32x4  __attribute__((ext_vector_type(4)));

#define NB 8
#define NQ 900
#define DM 256
#define NHEADS 8
#define DHEAD 32
#define NFF 1024
#define NLAY 6
#define NS 13294
#define BQ (NB*NQ)            // 7200
#define LN_EPS 1e-5f
#define ATT_SCALE 0.17677669529663687f   // 1/sqrt(32)
#define SAK 40                // LDS row stride (bf16): 80B — measured ~2-way (free)
#define VWS 264               // vp kernel: A LDS row stride (256+8): 2-way banks

__device__ __forceinline__ float bfd(const bf16* p, size_t i){ return __bfloat162float(p[i]); }

// mode: 0 = fp32 (internal), 1 = bf16 (internal), 2 = external (dtype per flag)
__device__ __forceinline__ float ldv(const void* p, size_t i, int mode, bool extF32)
{
    if (mode == 0) return ((const float*)p)[i];
    if (mode == 1) return bfd((const bf16*)p, i);
    return extF32 ? ((const float*)p)[i] : bfd((const bf16*)p, i);
}

// unpack 8 bf16 (16B) to floats
__device__ __forceinline__ void unpack8(uint4 u, float* t)
{
    t[0] = __uint_as_float((u.x & 0xffffu) << 16);
    t[1] = __uint_as_float(u.x & 0xffff0000u);
    t[2] = __uint_as_float((u.y & 0xffffu) << 16);
    t[3] = __uint_as_float(u.y & 0xffff0000u);
    t[4] = __uint_as_float((u.z & 0xffffu) << 16);
    t[5] = __uint_as_float(u.z & 0xffff0000u);
    t[6] = __uint_as_float((u.w & 0xffffu) << 16);
    t[7] = __uint_as_float(u.w & 0xffff0000u);
}

// ---------------------------------------------------------------------------
__global__ __launch_bounds__(256) void detect_dtype(const void* __restrict__ tgt,
        float* __restrict__ flag)
{
    __shared__ float red[256];
    int t = threadIdx.x;
    const unsigned short* u = (const unsigned short*)tgt;
    float m = 0.f;
    for (int i = t; i < 2048; i += 256) {
        unsigned int bits = ((unsigned int)u[i]) << 16;
        float v = fabsf(__uint_as_float(bits));
        if (!isfinite(v)) v = 1e30f;
        m = fmaxf(m, v);
    }
    red[t] = m;
    __syncthreads();
    for (int st = 128; st; st >>= 1) {
        if (t < st) red[t] = fmaxf(red[t], red[t + st]);
        __syncthreads();
    }
    if (t == 0) flag[0] = (red[0] > 1e8f) ? 1.f : 0.f;
}

// ---------------------------------------------------------------------------
__global__ __launch_bounds__(256) void convert_w(const void* __restrict__ src,
        bf16* __restrict__ dst, const float* __restrict__ flagp)
{
    const bool ef = flagp[0] > 0.5f;
    size_t base = ((size_t)blockIdx.x * 256 + threadIdx.x) * 8;
    if (ef) {
        const float* s = (const float*)src + base;
        float4 f0 = *(const float4*)s;
        float4 f1 = *(const float4*)(s + 4);
        union { bf16 a[8]; uint4 u; } t;
        t.a[0] = __float2bfloat16(f0.x); t.a[1] = __float2bfloat16(f0.y);
        t.a[2] = __float2bfloat16(f0.z); t.a[3] = __float2bfloat16(f0.w);
        t.a[4] = __float2bfloat16(f1.x); t.a[5] = __float2bfloat16(f1.y);
        t.a[6] = __float2bfloat16(f1.z); t.a[7] = __float2bfloat16(f1.w);
        *(uint4*)(dst + base) = t.u;
    } else {
        *(uint4*)(dst + base) = *(const uint4*)((const bf16*)src + base);
    }
}

// ---------------------------------------------------------------------------
// Value-projection GEMM, W-in-registers, 8 waves/block (512 thr).
// Each wave owns a 32-col W slice: 16 bf16x8 frags = 64 VGPR (vs 128 for the
// 64-col quarter) -> total ~150 regs/wave -> 3 waves/SIMD (launch_bounds 3).
// LDS holds only the 64-row A tile (33.8 KB) -> 3 blocks/CU (24 waves/CU).
// Per tile per wave: 32 A ds_reads : 64 MFMAs, zero W ds_reads.
// grid: 831 blocks x exactly 2 tiles (1662 tiles total).
// ---------------------------------------------------------------------------
__global__ __launch_bounds__(512, 3) void gemm_vp(const void* __restrict__ A,
        const bf16* __restrict__ Wb, const void* __restrict__ bias,
        bf16* __restrict__ C, int M, const float* __restrict__ flagp)
{
    const bool ef = flagp[0] > 0.5f;          // true -> A is fp32
    __shared__ __align__(16) bf16 Al[64 * VWS];    // 33792 B
    const int tid = threadIdx.x;
    const int w = tid >> 6, lane = tid & 63, lm = lane & 15, lq = lane >> 4;
    const int wq = w * 32;                    // wave's 32-col slice

    // ---- preload W slice into registers (once; L2-hot) ----
    bf16x8 wf[2][8];
    #pragma unroll
    for (int nt = 0; nt < 2; nt++)
        #pragma unroll
        for (int ks = 0; ks < 8; ks++)
            wf[nt][ks] = *(const bf16x8*)(Wb +
                (size_t)(wq + nt * 16 + lm) * 256 + ks * 32 + lq * 8);

    float bv[2];
    #pragma unroll
    for (int nt = 0; nt < 2; nt++) bv[nt] = ldv(bias, wq + nt * 16 + lm, 2, ef);

    const int arow_l = tid >> 3;              // 0..63
    const int acol   = (tid & 7) * 32;        // 0,32,..,224

    const int ntiles = (M + 63) / 64;
    for (int tile = blockIdx.x; tile < ntiles; tile += gridDim.x) {
        const int m0 = tile * 64;
        __syncthreads();                      // prior tile's reads done
        // ---- stage A tile [64][256]: 32 cols per thread ----
        {
            const int grow = m0 + arow_l;
            if (grow < M) {
                if (ef) {
                    const float* ap = (const float*)A + (size_t)grow * 256 + acol;
                    #pragma unroll
                    for (int j = 0; j < 4; j++) {
                        float4 f0 = *(const float4*)(ap + j * 8);
                        float4 f1 = *(const float4*)(ap + j * 8 + 4);
                        union { bf16 a[8]; uint4 u; } t;
                        t.a[0] = __float2bfloat16(f0.x); t.a[1] = __float2bfloat16(f0.y);
                        t.a[2] = __float2bfloat16(f0.z); t.a[3] = __float2bfloat16(f0.w);
                        t.a[4] = __float2bfloat16(f1.x); t.a[5] = __float2bfloat16(f1.y);
                        t.a[6] = __float2bfloat16(f1.z); t.a[7] = __float2bfloat16(f1.w);
                        *(uint4*)&Al[arow_l * VWS + acol + j * 8] = t.u;
                    }
                } else {
                    const bf16* ap = (const bf16*)A + (size_t)grow * 256 + acol;
                    #pragma unroll
                    for (int j = 0; j < 4; j++)
                        *(uint4*)&Al[arow_l * VWS + acol + j * 8] =
                            *(const uint4*)(ap + j * 8);
                }
            } else {
                uint4 z = make_uint4(0u, 0u, 0u, 0u);
                #pragma unroll
                for (int j = 0; j < 4; j++)
                    *(uint4*)&Al[arow_l * VWS + acol + j * 8] = z;
            }
        }
        __syncthreads();                      // A tile ready

        // ---- compute: 8 K-steps x (4 m-frags x 2 n-frags) = 64 MFMAs ----
        f32x4 acc[4][2];
        #pragma unroll
        for (int mi = 0; mi < 4; mi++)
            #pragma unroll
            for (int nt = 0; nt < 2; nt++)
                acc[mi][nt] = (f32x4){0.f, 0.f, 0.f, 0.f};

        #pragma unroll
        for (int ks = 0; ks < 8; ks++) {
            bf16x8 af[4];
            #pragma unroll
            for (int mi = 0; mi < 4; mi++)
                af[mi] = *(const bf16x8*)&Al[(mi * 16 + lm) * VWS + ks * 32 + lq * 8];
            #pragma unroll
            for (int nt = 0; nt < 2; nt++)
                #pragma unroll
                for (int mi = 0; mi < 4; mi++)
                    acc[mi][nt] = __builtin_amdgcn_mfma_f32_16x16x32_bf16(
                                      af[mi], wf[nt][ks], acc[mi][nt], 0, 0, 0);
        }

        // ---- write C tile (bf16) ----
        #pragma unroll
        for (int mi = 0; mi < 4; mi++) {
            #pragma unroll
            for (int r = 0; r < 4; r++) {
                int m = m0 + mi * 16 + lq * 4 + r;
                if (m >= M) continue;
                #pragma unroll
                for (int nt = 0; nt < 2; nt++) {
                    int col = wq + nt * 16 + lm;
                    C[(size_t)m * 256 + col] = __float2bfloat16(acc[mi][nt][r] + bv[nt]);
                }
            }
        }
    }
}

// ---------------------------------------------------------------------------
// stage A tile [32][32] : thread t -> row t>>3, col (t&7)*4  (uint2 / float4)
// ---------------------------------------------------------------------------
__device__ __forceinline__ void stage_a32(bf16* As, const void* A, bool a_bf16,
        int m0, int M, int K, int k0, int tid)
{
    const int row = tid >> 3, col = (tid & 7) * 4;
    const int arow = m0 + row;
    union { bf16 a[4]; uint2 u; } t;
    if (arow < M) {
        size_t base = (size_t)arow * K + k0 + col;
        if (a_bf16) {
            t.u = *(const uint2*)((const bf16*)A + base);
        } else {
            float4 f = *(const float4*)((const float*)A + base);
            t.a[0] = __float2bfloat16(f.x); t.a[1] = __float2bfloat16(f.y);
            t.a[2] = __float2bfloat16(f.z); t.a[3] = __float2bfloat16(f.w);
        }
    } else {
        t.u = make_uint2(0u, 0u);
    }
    *(uint2*)&As[row * SAK + col] = t.u;
}

// ---------------------------------------------------------------------------
// Plain GEMM, tile 32 x 256. grid: (N/256, ceil(M/32)).
// ---------------------------------------------------------------------------
__global__ __launch_bounds__(256) void gemm_a(const void* __restrict__ A, int amode,
        const bf16* __restrict__ Wb, const void* __restrict__ bias,
        void* __restrict__ C, int cmode, int M, int N, int K, int relu,
        const float* __restrict__ flagp)
{
    const bool ef = flagp[0] > 0.5f;
    const bool a_bf16 = (amode == 1) || (amode == 2 && !ef);
    __shared__ __align__(16) bf16 As[32 * SAK];
    __shared__ __align__(16) bf16 Ws[256 * SAK];
    const int tid = threadIdx.x;
    const int m0 = blockIdx.y * 32, n0 = blockIdx.x * 256;
    const int w = tid >> 6, lane = tid & 63, lm = lane & 15, lq = lane >> 4;
    const int wr = w >> 1, wc = w & 1;
    const int srow = tid >> 2, scol = (tid & 3) * 8;

    f32x4 acc[8];
    #pragma unroll
    for (int nt = 0; nt < 8; nt++) acc[nt] = (f32x4){0.f, 0.f, 0.f, 0.f};

    for (int k0 = 0; k0 < K; k0 += 32) {
        stage_a32(As, A, a_bf16, m0, M, K, k0, tid);
        #pragma unroll
        for (int it = 0; it < 4; it++) {
            int rr = it * 64 + srow;
            *(uint4*)&Ws[rr * SAK + scol] =
                *(const uint4*)(Wb + (size_t)(n0 + rr) * K + k0 + scol);
        }
        __syncthreads();

        bf16x8 af = *(const bf16x8*)&As[(wr * 16 + lm) * SAK + lq * 8];
        #pragma unroll
        for (int nt = 0; nt < 8; nt++) {
            bf16x8 bfr = *(const bf16x8*)&Ws[(wc * 128 + nt * 16 + lm) * SAK + lq * 8];
            acc[nt] = __builtin_amdgcn_mfma_f32_16x16x32_bf16(af, bfr, acc[nt], 0, 0, 0);
        }
        __syncthreads();
    }

    #pragma unroll
    for (int nt = 0; nt < 8; nt++) {
        int n = n0 + wc * 128 + nt * 16 + lm;
        float bv = ldv(bias, n, 2, ef);
        #pragma unroll
        for (int r = 0; r < 4; r++) {
            int m = m0 + wr * 16 + lq * 4 + r;
            if (m >= M) continue;
            float v = acc[nt][r] + bv;
            if (relu) v = fmaxf(v, 0.f);
            size_t ci = (size_t)m * N + n;
            if (cmode == 0) ((float*)C)[ci] = v;
            else            ((bf16*)C)[ci] = __float2bfloat16(v);
        }
    }
}

// ---------------------------------------------------------------------------
// Fused GEMM (N=256) + bias + residual + LayerNorm. Tile 32 x 256.
// ---------------------------------------------------------------------------
__global__ __launch_bounds__(256) void gemm_ln(const bf16* __restrict__ A,
        const bf16* __restrict__ Wb, const void* __restrict__ bias,
        const float* __restrict__ res, const void* __restrict__ gw,
        const void* __restrict__ bw, float* __restrict__ out32,
        bf16* __restrict__ outbf, void* __restrict__ dout, size_t obase,
        const void* __restrict__ qp, int M, int K,
        const float* __restrict__ flagp)
{
    const bool ef = flagp[0] > 0.5f;
    __shared__ __align__(16) bf16 As[32 * SAK];
    __shared__ __align__(16) bf16 Ws[256 * SAK];
    const int tid = threadIdx.x;
    const int m0 = blockIdx.y * 32;
    const int w = tid >> 6, lane = tid & 63, lm = lane & 15, lq = lane >> 4;
    const int wr = w >> 1, wc = w & 1;
    const int srow = tid >> 2, scol = (tid & 3) * 8;

    f32x4 acc[8];
    #pragma unroll
    for (int nt = 0; nt < 8; nt++) acc[nt] = (f32x4){0.f, 0.f, 0.f, 0.f};

    for (int k0 = 0; k0 < K; k0 += 32) {
        stage_a32(As, A, true, m0, M, K, k0, tid);
        #pragma unroll
        for (int it = 0; it < 4; it++) {
            int rr = it * 64 + srow;
            *(uint4*)&Ws[rr * SAK + scol] =
                *(const uint4*)(Wb + (size_t)rr * K + k0 + scol);
        }
        __syncthreads();

        bf16x8 af = *(const bf16x8*)&As[(wr * 16 + lm) * SAK + lq * 8];
        #pragma unroll
        for (int nt = 0; nt < 8; nt++) {
            bf16x8 bfr = *(const bf16x8*)&Ws[(wc * 128 + nt * 16 + lm) * SAK + lq * 8];
            acc[nt] = __builtin_amdgcn_mfma_f32_16x16x32_bf16(af, bfr, acc[nt], 0, 0, 0);
        }
        __syncthreads();
    }

    float bias_c[8], gcol[8], bcol[8];
    #pragma unroll
    for (int nt = 0; nt < 8; nt++) {
        int col = wc * 128 + nt * 16 + lm;
        bias_c[nt] = ldv(bias, col, 2, ef);
        gcol[nt]   = ldv(gw,   col, 2, ef);
        bcol[nt]   = ldv(bw,   col, 2, ef);
    }
    #pragma unroll
    for (int r = 0; r < 4; r++) {
        int row = m0 + wr * 16 + lq * 4 + r;
        bool vr_ = row < M;
        #pragma unroll
        for (int nt = 0; nt < 8; nt++) {
            int col = wc * 128 + nt * 16 + lm;
            float rv = vr_ ? res[(size_t)row * DM + col] : 0.f;
            acc[nt][r] += bias_c[nt] + rv;
        }
    }

    float* red = (float*)As;
    float mu[4], rstd[4];
    #pragma unroll
    for (int r = 0; r < 4; r++) {
        float s = 0.f;
        #pragma unroll
        for (int nt = 0; nt < 8; nt++) s += acc[nt][r];
        s += __shfl_xor(s, 1, 64); s += __shfl_xor(s, 2, 64);
        s += __shfl_xor(s, 4, 64); s += __shfl_xor(s, 8, 64);
        if (lm == 0) red[(wr * 16 + lq * 4 + r) * 2 + wc] = s;
    }
    __syncthreads();
    #pragma unroll
    for (int r = 0; r < 4; r++) {
        int rl = wr * 16 + lq * 4 + r;
        mu[r] = (red[rl * 2] + red[rl * 2 + 1]) * (1.f / DM);
    }
    #pragma unroll
    for (int r = 0; r < 4; r++) {
        float q = 0.f;
        #pragma unroll
        for (int nt = 0; nt < 8; nt++) {
            float d = acc[nt][r] - mu[r];
            q += d * d;
        }
        q += __shfl_xor(q, 1, 64); q += __shfl_xor(q, 2, 64);
        q += __shfl_xor(q, 4, 64); q += __shfl_xor(q, 8, 64);
        if (lm == 0) red[64 + (wr * 16 + lq * 4 + r) * 2 + wc] = q;
    }
    __syncthreads();
    #pragma unroll
    for (int r = 0; r < 4; r++) {
        int rl = wr * 16 + lq * 4 + r;
        float var = (red[64 + rl * 2] + red[64 + rl * 2 + 1]) * (1.f / DM);
        rstd[r] = rsqrtf(var + LN_EPS);
    }

    #pragma unroll
    for (int r = 0; r < 4; r++) {
        int row = m0 + wr * 16 + lq * 4 + r;
        if (row >= M) continue;
        size_t rbase = (size_t)row * DM;
        #pragma unroll
        for (int nt = 0; nt < 8; nt++) {
            int col = wc * 128 + nt * 16 + lm;
            float o = (acc[nt][r] - mu[r]) * rstd[r] * gcol[nt] + bcol[nt];
            if (dout) {
                if (ef) ((float*)dout)[obase + rbase + col] = o;
                else    ((bf16*)dout)[obase + rbase + col] = __float2bfloat16(o);
            }
            float o2 = o + (qp ? ldv(qp, rbase + col, 2, ef) : 0.f);
            out32[rbase + col] = o2;
            outbf[rbase + col] = __float2bfloat16(o2);
        }
    }
}

// ---------------------------------------------------------------------------
// Fused sampling-offset + attention-weight GEMM: W = concat(so_w, aw_w) rows
// (N=384). Tile 32 x 128; grid (3, ceil(M/32)).
// ---------------------------------------------------------------------------
__global__ __launch_bounds__(256) void gemm_soaw(const bf16* __restrict__ A,
        const bf16* __restrict__ Wb, const void* __restrict__ b1,
        const void* __restrict__ b2, float* __restrict__ C1,
        float* __restrict__ C2, int M, const float* __restrict__ flagp)
{
    const bool ef = flagp[0] > 0.5f;
    const int K = DM;
    __shared__ __align__(16) bf16 As[32 * SAK];
    __shared__ __align__(16) bf16 Ws[128 * SAK];
    const int tid = threadIdx.x;
    const int m0 = blockIdx.y * 32, n0 = blockIdx.x * 128;
    const int w = tid >> 6, lane = tid & 63, lm = lane & 15, lq = lane >> 4;
    const int wr = w >> 1, wc = w & 1;
    const int srow = tid >> 2, scol = (tid & 3) * 8;

    f32x4 acc[4];
    #pragma unroll
    for (int nt = 0; nt < 4; nt++) acc[nt] = (f32x4){0.f, 0.f, 0.f, 0.f};

    for (int k0 = 0; k0 < K; k0 += 32) {
        stage_a32(As, A, true, m0, M, K, k0, tid);
        #pragma unroll
        for (int it = 0; it < 2; it++) {
            int rr = it * 64 + srow;
            *(uint4*)&Ws[rr * SAK + scol] =
                *(const uint4*)(Wb + (size_t)(n0 + rr) * K + k0 + scol);
        }
        __syncthreads();

        bf16x8 af = *(const bf16x8*)&As[(wr * 16 + lm) * SAK + lq * 8];
        #pragma unroll
        for (int nt = 0; nt < 4; nt++) {
            bf16x8 bfr = *(const bf16x8*)&Ws[(wc * 64 + nt * 16 + lm) * SAK + lq * 8];
            acc[nt] = __builtin_amdgcn_mfma_f32_16x16x32_bf16(af, bfr, acc[nt], 0, 0, 0);
        }
        __syncthreads();
    }

    float* Cd; const void* bsrc; int nst, c0;
    if (n0 < 256) { Cd = C1; bsrc = b1; nst = 256; c0 = n0; }
    else          { Cd = C2; bsrc = b2; nst = 128; c0 = n0 - 256; }

    #pragma unroll
    for (int nt = 0; nt < 4; nt++) {
        int cl = wc * 64 + nt * 16 + lm;
        float bv = ldv(bsrc, c0 + cl, 2, ef);
        #pragma unroll
        for (int r = 0; r < 4; r++) {
            int m = m0 + wr * 16 + lq * 4 + r;
            if (m >= M) continue;
            Cd[(size_t)m * nst + c0 + cl] = acc[nt][r] + bv;
        }
    }
}

// ---------------------------------------------------------------------------
__global__ __launch_bounds__(256) void add_qpos(const void* __restrict__ a, int amode,
        const void* __restrict__ qp, float* __restrict__ o, bf16* __restrict__ ob,
        const float* __restrict__ flagp)
{
    const bool ef = flagp[0] > 0.5f;
    int i = blockIdx.x * 256 + threadIdx.x;
    float v = ldv(a, i, amode, ef) + ldv(qp, i, 2, ef);
    o[i]  = v;
    ob[i] = __float2bfloat16(v);
}

// ---------------------------------------------------------------------------
// MFMA flash MHA. grid (15 qtiles, 8 h, 8 b), 256 thr = 4 waves.
// ---------------------------------------------------------------------------
__global__ __launch_bounds__(256) void mha_mfma(const bf16* __restrict__ qkv,
        bf16* __restrict__ out)
{
    const int qt = blockIdx.x, h = blockIdx.y, b = blockIdx.z;
    const int q0 = qt * 64;
    const int tid = threadIdx.x;
    const int w = tid >> 6, lane = tid & 63;
    const int lm = lane & 15, lq = lane >> 4;
    const int srow = tid >> 2, sc = (tid & 3) * 8;

    __shared__ __align__(16) bf16 Qs[64][SAK];
    __shared__ __align__(16) bf16 Ks[64][SAK];
    __shared__ __align__(16) bf16 Vt[32][66];
    __shared__ __align__(16) bf16 Pt[64][66];

    const bf16* base = qkv + (size_t)b * NQ * 768;

    {
        bf16 tmp[8];
        if (q0 + srow < NQ) {
            uint4 u = *(const uint4*)(base + (size_t)(q0 + srow) * 768 + h * DHEAD + sc);
            float t[8]; unpack8(u, t);
            #pragma unroll
            for (int i = 0; i < 8; i++) tmp[i] = __float2bfloat16(t[i] * ATT_SCALE);
        } else {
            #pragma unroll
            for (int i = 0; i < 8; i++) tmp[i] = __float2bfloat16(0.f);
        }
        *(uint4*)&Qs[srow][sc] = *(const uint4*)tmp;
    }
    __syncthreads();
    const bf16x8 qf = *(const bf16x8*)&Qs[w * 16 + lm][lq * 8];

    f32x4 O[2] = {{0.f,0.f,0.f,0.f},{0.f,0.f,0.f,0.f}};
    float mrow = -1e30f, lrow = 0.f;

    for (int k0 = 0; k0 < NQ; k0 += 64) {
        __syncthreads();
        {
            uint4 uk = {0u,0u,0u,0u}, uv = {0u,0u,0u,0u};
            if (k0 + srow < NQ) {
                const bf16* rp = base + (size_t)(k0 + srow) * 768 + h * DHEAD + sc;
                uk = *(const uint4*)(rp + 256);
                uv = *(const uint4*)(rp + 512);
            }
            *(uint4*)&Ks[srow][sc] = uk;
            const bf16* vv = (const bf16*)&uv;
            #pragma unroll
            for (int i = 0; i < 8; i++) Vt[sc + i][srow] = vv[i];
        }
        __syncthreads();

        float sv[16];
        #pragma unroll
        for (int mt = 0; mt < 4; mt++) {
            bf16x8 kf = *(const bf16x8*)&Ks[mt * 16 + lm][lq * 8];
            f32x4 d = __builtin_amdgcn_mfma_f32_16x16x32_bf16(kf, qf,
                        (f32x4){0.f,0.f,0.f,0.f}, 0, 0, 0);
            sv[mt*4+0] = d[0]; sv[mt*4+1] = d[1]; sv[mt*4+2] = d[2]; sv[mt*4+3] = d[3];
        }
        #pragma unroll
        for (int mt = 0; mt < 4; mt++)
            #pragma unroll
            for (int r = 0; r < 4; r++)
                if (k0 + mt * 16 + lq * 4 + r >= NQ) sv[mt*4+r] = -1e30f;

        float tmax = sv[0];
        #pragma unroll
        for (int j = 1; j < 16; j++) tmax = fmaxf(tmax, sv[j]);
        tmax = fmaxf(tmax, __shfl_xor(tmax, 16, 64));
        tmax = fmaxf(tmax, __shfl_xor(tmax, 32, 64));
        float mnew = fmaxf(mrow, tmax);
        float alpha = __expf(mrow - mnew);
        mrow = mnew;
        float psum = 0.f;
        #pragma unroll
        for (int j = 0; j < 16; j++) {
            float p = __expf(sv[j] - mnew);
            sv[j] = p; psum += p;
        }
        psum += __shfl_xor(psum, 16, 64);
        psum += __shfl_xor(psum, 32, 64);
        lrow = lrow * alpha + psum;

        #pragma unroll
        for (int mt = 0; mt < 4; mt++)
            #pragma unroll
            for (int r = 0; r < 4; r++)
                Pt[mt * 16 + lq * 4 + r][w * 16 + lm] = __float2bfloat16(sv[mt*4+r]);

        #pragma unroll
        for (int mt = 0; mt < 2; mt++)
            #pragma unroll
            for (int r = 0; r < 4; r++) O[mt][r] *= alpha;
        #pragma unroll
        for (int ks = 0; ks < 2; ks++) {
            union { bf16 a[8]; bf16x8 v; } pf;
            #pragma unroll
            for (int j = 0; j < 8; j++)
                pf.a[j] = Pt[ks * 32 + lq * 8 + j][w * 16 + lm];
            #pragma unroll
            for (int mt = 0; mt < 2; mt++) {
                bf16x8 vf = *(const bf16x8*)&Vt[mt * 16 + lm][ks * 32 + lq * 8];
                O[mt] = __builtin_amdgcn_mfma_f32_16x16x32_bf16(vf, pf.v, O[mt], 0, 0, 0);
            }
        }
    }

    int q = q0 + w * 16 + lm;
    if (q < NQ) {
        float invl = 1.f / lrow;
        bf16* op = out + ((size_t)(b * NQ + q)) * DM + h * DHEAD;
        #pragma unroll
        for (int mt = 0; mt < 2; mt++)
            #pragma unroll
            for (int r = 0; r < 4; r++)
                op[mt * 16 + lq * 4 + r] = __float2bfloat16(O[mt][r] * invl);
    }
}

// ---------------------------------------------------------------------------
// MSDA sampling, 8 queries/block. Thread = (query qi, head h, chan-group cg).
// ---------------------------------------------------------------------------
__global__ __launch_bounds__(256) void msda_sample8(const bf16* __restrict__ value,
        const float* __restrict__ off, const float* __restrict__ aw,
        const void* __restrict__ refp, const void* __restrict__ vr,
        bf16* __restrict__ out, const float* __restrict__ flagp)
{
    const bool ef = flagp[0] > 0.5f;
    const int tid = threadIdx.x;
    const int bq0 = blockIdx.x * 8;

    __shared__ float sOff[8][256];
    __shared__ float sAw[8][128];
    __shared__ float sref[8][2];
    __shared__ float svrq[8][8];

    {
        const float* osrc = off + (size_t)bq0 * 256;
        #pragma unroll
        for (int i = 0; i < 2; i++) {
            int e = i * 1024 + tid * 4;
            *(float4*)&sOff[e >> 8][e & 255] = *(const float4*)(osrc + e);
        }
        int e2 = tid * 4;
        *(float4*)&sAw[e2 >> 7][e2 & 127] = *(const float4*)(aw + (size_t)bq0 * 128 + e2);
    }
    if (tid < 16) sref[tid >> 1][tid & 1] = ldv(refp, (size_t)(bq0 + (tid >> 1)) * 2 + (tid & 1), 2, ef);
    if (tid < 64) {
        int qi = tid >> 3, j = tid & 7;
        int b = (bq0 + qi) / NQ;
        svrq[qi][j] = ldv(vr, b * 8 + j, 2, ef);
    }
    __syncthreads();

    if (tid < 64) {
        int qi = tid >> 3, h = tid & 7;
        float* p = &sAw[qi][h * 16];
        float mx = -1e30f;
        #pragma unroll
        for (int j = 0; j < 16; j++) mx = fmaxf(mx, p[j]);
        float s = 0.f;
        #pragma unroll
        for (int j = 0; j < 16; j++) { float e = __expf(p[j] - mx); p[j] = e; s += e; }
        float inv = 1.f / s;
        #pragma unroll
        for (int j = 0; j < 16; j++) p[j] *= inv;
    }
    __syncthreads();

    const int qi = tid >> 5, sub = tid & 31;
    const int h = sub >> 2, cg = sub & 3;
    const int bq = bq0 + qi;
    const int b = bq / NQ;
    const bf16* vb = value + (size_t)b * NS * DM + h * DHEAD + cg * 8;

    float acc[8];
    #pragma unroll
    for (int j = 0; j < 8; j++) acc[j] = 0.f;

    const int HS[4] = {100, 50, 25, 13};
    const int ST[4] = {0, 10000, 12500, 13125};
    #pragma unroll
    for (int lvl = 0; lvl < 4; lvl++) {
        const int W_ = HS[lvl], H_ = HS[lvl], st = ST[lvl];
        float rx = sref[qi][0] * svrq[qi][lvl * 2 + 0] * (float)W_;
        float ry = sref[qi][1] * svrq[qi][lvl * 2 + 1] * (float)H_;
        #pragma unroll
        for (int p = 0; p < 4; p++) {
            int oi = h * 32 + lvl * 8 + p * 2;
            float x = fminf(fmaxf(rx + sOff[qi][oi]     - 0.5f, -4.f), (float)W_ + 4.f);
            float y = fminf(fmaxf(ry + sOff[qi][oi + 1] - 0.5f, -4.f), (float)H_ + 4.f);
            float x0f = floorf(x), y0f = floorf(y);
            float wx = x - x0f, wy = y - y0f;
            int x0 = (int)x0f, y0 = (int)y0f;
            int x1i = x0 + 1, y1i = y0 + 1;
            bool vx0 = (x0 >= 0) && (x0 < W_), vx1 = (x1i >= 0) && (x1i < W_);
            bool vy0 = (y0 >= 0) && (y0 < H_), vy1 = (y1i >= 0) && (y1i < H_);
            float g[8];
            #pragma unroll
            for (int j = 0; j < 8; j++) g[j] = 0.f;
            float t[8];
            if (vy0) {
                int rowo = (st + y0 * W_) * DM;
                if (vx0) {
                    uint4 u = *(const uint4*)(vb + rowo + x0 * DM);
                    unpack8(u, t);
                    float wgt = (1.f - wx) * (1.f - wy);
                    #pragma unroll
                    for (int j = 0; j < 8; j++) g[j] += wgt * t[j];
                }
                if (vx1) {
                    uint4 u = *(const uint4*)(vb + rowo + x1i * DM);
                    unpack8(u, t);
                    float wgt = wx * (1.f - wy);
                    #pragma unroll
                    for (int j = 0; j < 8; j++) g[j] += wgt * t[j];
                }
            }
            if (vy1) {
                int rowo = (st + y1i * W_) * DM;
                if (vx0) {
                    uint4 u = *(const uint4*)(vb + rowo + x0 * DM);
                    unpack8(u, t);
                    float wgt = (1.f - wx) * wy;
                    #pragma unroll
                    for (int j = 0; j < 8; j++) g[j] += wgt * t[j];
                }
                if (vx1) {
                    uint4 u = *(const uint4*)(vb + rowo + x1i * DM);
                    unpack8(u, t);
                    float wgt = wx * wy;
                    #pragma unroll
                    for (int j = 0; j < 8; j++) g[j] += wgt * t[j];
                }
            }
            float a = sAw[qi][h * 16 + lvl * 4 + p];
            #pragma unroll
            for (int j = 0; j < 8; j++) acc[j] += a * g[j];
        }
    }

    union { bf16 t[8]; uint4 u; } pk;
    #pragma unroll
    for (int j = 0; j < 8; j++) pk.t[j] = __float2bfloat16(acc[j]);
    *(uint4*)(out + (size_t)bq * DM + h * DHEAD + cg * 8) = pk.u;
}

// ---------------------------------------------------------------------------
__global__ __launch_bounds__(256) void copy_refs(const void* __restrict__ refp,
        void* __restrict__ out, const float* __restrict__ flagp)
{
    const bool ef = flagp[0] > 0.5f;
    int i = blockIdx.x * 256 + threadIdx.x;
    if (i >= NLAY * BQ * 2) return;
    float v = ldv(refp, i % (BQ * 2), 2, ef);
    size_t oi = (size_t)NLAY * BQ * DM + i;
    if (ef) ((float*)out)[oi] = v;
    else    ((bf16*)out)[oi] = __float2bfloat16(v);
}

// ---------------------------------------------------------------------------
extern "C" void kernel_launch(void* const* d_in, const int* in_sizes, int n_in,
                              void* d_out, int out_size, void* d_ws, size_t ws_size,
                              hipStream_t stream)
{
    const void* tgt     = d_in[0];
    const void* refp    = d_in[1];
    const void* memory  = d_in[2];
    const void* vr      = d_in[5];
    const void* qp      = d_in[6];
    const void* sa_in_w = d_in[7];
    const void* sa_in_b = d_in[8];
    const void* sa_out_w= d_in[9];
    const void* sa_out_b= d_in[10];
    const void* n1_g    = d_in[11];
    const void* n1_b    = d_in[12];
    const void* n2_g    = d_in[13];
    const void* n2_b    = d_in[14];
    const void* n3_g    = d_in[15];
    const void* n3_b    = d_in[16];
    const void* vp_w    = d_in[17];
    const void* vp_b    = d_in[18];
    const void* so_w    = d_in[19];
    const void* so_b    = d_in[20];
    const void* aw_w    = d_in[21];
    const void* aw_b    = d_in[22];
    const void* op_w    = d_in[23];
    const void* op_b    = d_in[24];
    const void* ff1_w   = d_in[25];
    const void* ff1_b   = d_in[26];
    const void* ff2_w   = d_in[27];
    const void* ff2_b   = d_in[28];

    // ---- workspace layout ----
    char* w = (char*)d_ws;
    float* flagp  = (float*)w;  w += 256;
    bf16*  value  = (bf16*)w;   w += (size_t)NB * NS * DM * 2;   // 54.45 MB
    float* outbuf = (float*)w;  w += (size_t)BQ * DM * 4;
    float* x1samp = (float*)w;  w += (size_t)BQ * DM * 4;
    bf16*  bigb   = (bf16*)w;   w += (size_t)BQ * NFF * 2;       // qkv / ffn hidden
    float* attoff = (float*)w;  w += (size_t)BQ * DM * 4;        // sampling offsets
    float* awb    = (float*)w;  w += (size_t)BQ * 128 * 4;       // aw logits
    bf16*  abuf   = (bf16*)w;   w += (size_t)BQ * DM * 2;        // x1/mha/msda bf16
    bf16*  outbf  = (bf16*)w;   w += (size_t)BQ * DM * 2;        // ln bf16 dup
    // pre-converted bf16 weights
    bf16* wb_sa_in = (bf16*)w;  w += (size_t)768 * 256 * 2;
    bf16* wb_sa_out= (bf16*)w;  w += (size_t)256 * 256 * 2;
    bf16* wb_soaw  = (bf16*)w;  w += (size_t)384 * 256 * 2;      // so(256) ++ aw(128)
    bf16* wb_op    = (bf16*)w;  w += (size_t)256 * 256 * 2;
    bf16* wb_ff1   = (bf16*)w;  w += (size_t)NFF * 256 * 2;
    bf16* wb_ff2   = (bf16*)w;  w += (size_t)256 * NFF * 2;
    bf16* wb_vp    = (bf16*)w;  w += (size_t)256 * 256 * 2;

    const int gy = (BQ + 31) / 32;      // 225
    const int MV = NB * NS;             // 106352

    // 0) detect external dtype, pre-convert weights to bf16
    detect_dtype<<<1, 256, 0, stream>>>(tgt, flagp);
    convert_w<<< 96, 256, 0, stream>>>(sa_in_w,  wb_sa_in,  flagp);
    convert_w<<< 32, 256, 0, stream>>>(sa_out_w, wb_sa_out, flagp);
    convert_w<<< 32, 256, 0, stream>>>(so_w,     wb_soaw,   flagp);
    convert_w<<< 16, 256, 0, stream>>>(aw_w,     wb_soaw + 256 * 256, flagp);
    convert_w<<< 32, 256, 0, stream>>>(op_w,     wb_op,     flagp);
    convert_w<<<128, 256, 0, stream>>>(ff1_w,    wb_ff1,    flagp);
    convert_w<<<128, 256, 0, stream>>>(ff2_w,    wb_ff2,    flagp);
    convert_w<<< 32, 256, 0, stream>>>(vp_w,     wb_vp,     flagp);

    // 1) value projection: W-in-registers GEMM, 8 waves/block, 3 blocks/CU
    gemm_vp<<<831, 512, 0, stream>>>(memory, wb_vp, vp_b, value, MV, flagp);

    // 2) inter_refs output
    copy_refs<<<(NLAY * BQ * 2 + 255) / 256, 256, 0, stream>>>(refp, d_out, flagp);

    // 3) x1 = tgt + query_pos (layer 0 only; later layers fused into ff2 LN)
    add_qpos<<<BQ * DM / 256, 256, 0, stream>>>(tgt, 2, qp, x1samp, abuf, flagp);

    for (int l = 0; l < NLAY; l++) {
        // self-attention
        gemm_a<<<dim3(768/256, gy), 256, 0, stream>>>(
            abuf, 1, wb_sa_in, sa_in_b, bigb, 1, BQ, 768, DM, 0, flagp);
        mha_mfma<<<dim3(15, NHEADS, NB), 256, 0, stream>>>(bigb, abuf);
        gemm_ln<<<dim3(1, gy), 256, 0, stream>>>(
            abuf, wb_sa_out, sa_out_b, x1samp, n1_g, n1_b,
            outbuf, outbf, nullptr, 0, nullptr, BQ, DM, flagp);

        // MSDA: fused so+aw GEMM, 8-query sampling w/ inline softmax, op+LN2
        gemm_soaw<<<dim3(3, gy), 256, 0, stream>>>(
            outbf, wb_soaw, so_b, aw_b, attoff, awb, BQ, flagp);
        msda_sample8<<<BQ / 8, 256, 0, stream>>>(value, attoff, awb, refp, vr, abuf, flagp);
        gemm_ln<<<dim3(1, gy), 256, 0, stream>>>(
            abuf, wb_op, op_b, outbuf, n2_g, n2_b,
            outbuf, outbf, nullptr, 0, nullptr, BQ, DM, flagp);

        // FFN: ff1 (relu, bf16 hidden), ff2 + LN3 + d_out slice + next x1(+qp)
        gemm_a<<<dim3(NFF/256, gy), 256, 0, stream>>>(
            outbf, 1, wb_ff1, ff1_b, bigb, 1, BQ, NFF, DM, 1, flagp);
        gemm_ln<<<dim3(1, gy), 256, 0, stream>>>(
            bigb, wb_ff2, ff2_b, outbuf, n3_g, n3_b,
            x1samp, abuf, d_out, (size_t)l * BQ * DM, qp, BQ, NFF, flagp);
    }
}

// Round 9
// 1482.715 us; speedup vs baseline: 1.0331x; 1.0331x over previous
//
#include <hip/hip_runtime.h>
#include <hip/hip_bf16.h>

typedef __hip_bfloat16 bf16;
typedef __bf16 bf16x8 __attribute__((ext_vector_type(8)));
typedef float  f32x4  __attribute__((ext_vector_type(4)));

#define NB 8
#define NQ 900
#define DM 256
#define NHEADS 8
#define DHEAD 32
#define NFF 1024
#define NLAY 6
#define NS 13294
#define BQ (NB*NQ)            // 7200
#define LN_EPS 1e-5f
#define ATT_SCALE 0.17677669529663687f   // 1/sqrt(32)
#define SAK 40                // LDS row stride (bf16): 80B — measured ~2-way (free)
#define VWS 264               // vp kernel: A LDS row stride (256+8): 2-way banks
#define PSK 88                // mha P row stride (176B, 16B-aligned, ~2-way banks)

__device__ __forceinline__ float bfd(const bf16* p, size_t i){ return __bfloat162float(p[i]); }

// mode: 0 = fp32 (internal), 1 = bf16 (internal), 2 = external (dtype per flag)
__device__ __forceinline__ float ldv(const void* p, size_t i, int mode, bool extF32)
{
    if (mode == 0) return ((const float*)p)[i];
    if (mode == 1) return bfd((const bf16*)p, i);
    return extF32 ? ((const float*)p)[i] : bfd((const bf16*)p, i);
}

// unpack 8 bf16 (16B) to floats
__device__ __forceinline__ void unpack8(uint4 u, float* t)
{
    t[0] = __uint_as_float((u.x & 0xffffu) << 16);
    t[1] = __uint_as_float(u.x & 0xffff0000u);
    t[2] = __uint_as_float((u.y & 0xffffu) << 16);
    t[3] = __uint_as_float(u.y & 0xffff0000u);
    t[4] = __uint_as_float((u.z & 0xffffu) << 16);
    t[5] = __uint_as_float(u.z & 0xffff0000u);
    t[6] = __uint_as_float((u.w & 0xffffu) << 16);
    t[7] = __uint_as_float(u.w & 0xffff0000u);
}

// ---------------------------------------------------------------------------
__global__ __launch_bounds__(256) void detect_dtype(const void* __restrict__ tgt,
        float* __restrict__ flag)
{
    __shared__ float red[256];
    int t = threadIdx.x;
    const unsigned short* u = (const unsigned short*)tgt;
    float m = 0.f;
    for (int i = t; i < 2048; i += 256) {
        unsigned int bits = ((unsigned int)u[i]) << 16;
        float v = fabsf(__uint_as_float(bits));
        if (!isfinite(v)) v = 1e30f;
        m = fmaxf(m, v);
    }
    red[t] = m;
    __syncthreads();
    for (int st = 128; st; st >>= 1) {
        if (t < st) red[t] = fmaxf(red[t], red[t + st]);
        __syncthreads();
    }
    if (t == 0) flag[0] = (red[0] > 1e8f) ? 1.f : 0.f;
}

// ---------------------------------------------------------------------------
__global__ __launch_bounds__(256) void convert_w(const void* __restrict__ src,
        bf16* __restrict__ dst, const float* __restrict__ flagp)
{
    const bool ef = flagp[0] > 0.5f;
    size_t base = ((size_t)blockIdx.x * 256 + threadIdx.x) * 8;
    if (ef) {
        const float* s = (const float*)src + base;
        float4 f0 = *(const float4*)s;
        float4 f1 = *(const float4*)(s + 4);
        union { bf16 a[8]; uint4 u; } t;
        t.a[0] = __float2bfloat16(f0.x); t.a[1] = __float2bfloat16(f0.y);
        t.a[2] = __float2bfloat16(f0.z); t.a[3] = __float2bfloat16(f0.w);
        t.a[4] = __float2bfloat16(f1.x); t.a[5] = __float2bfloat16(f1.y);
        t.a[6] = __float2bfloat16(f1.z); t.a[7] = __float2bfloat16(f1.w);
        *(uint4*)(dst + base) = t.u;
    } else {
        *(uint4*)(dst + base) = *(const uint4*)((const bf16*)src + base);
    }
}

// ---------------------------------------------------------------------------
// Value-projection GEMM, W-in-registers (round-7 proven config: 256 thr,
// 4 waves, 64-col W quarter per wave = 128 VGPR held, 2 blocks/CU).
// grid: 512 persistent blocks, stride over ceil(M/64) tiles.
// ---------------------------------------------------------------------------
__global__ __launch_bounds__(256, 2) void gemm_vp(const void* __restrict__ A,
        const bf16* __restrict__ Wb, const void* __restrict__ bias,
        bf16* __restrict__ C, int M, const float* __restrict__ flagp)
{
    const bool ef = flagp[0] > 0.5f;          // true -> A is fp32
    __shared__ __align__(16) bf16 Al[64 * VWS];    // 33792 B
    const int tid = threadIdx.x;
    const int w = tid >> 6, lane = tid & 63, lm = lane & 15, lq = lane >> 4;
    const int wq = w * 64;                    // wave's column quarter

    // ---- preload W quarter into registers (once; L2-hot) ----
    bf16x8 wf[4][8];
    #pragma unroll
    for (int nt = 0; nt < 4; nt++)
        #pragma unroll
        for (int ks = 0; ks < 8; ks++)
            wf[nt][ks] = *(const bf16x8*)(Wb +
                (size_t)(wq + nt * 16 + lm) * 256 + ks * 32 + lq * 8);

    float bv[4];
    #pragma unroll
    for (int nt = 0; nt < 4; nt++) bv[nt] = ldv(bias, wq + nt * 16 + lm, 2, ef);

    const int arow_l = tid >> 2;              // 0..63
    const int asub   = tid & 3;

    const int ntiles = (M + 63) / 64;
    for (int tile = blockIdx.x; tile < ntiles; tile += gridDim.x) {
        const int m0 = tile * 64;
        __syncthreads();                      // prior tile's reads done
        // ---- stage A tile [64][256] ----
        {
            const int grow = m0 + arow_l;
            if (grow < M) {
                if (ef) {
                    const float* ap = (const float*)A + (size_t)grow * 256;
                    #pragma unroll
                    for (int j = 0; j < 16; j++) {
                        int colf = j * 16 + asub * 4;    // quad covers 64B
                        float4 f = *(const float4*)(ap + colf);
                        union { bf16 a[4]; uint2 u; } t;
                        t.a[0] = __float2bfloat16(f.x); t.a[1] = __float2bfloat16(f.y);
                        t.a[2] = __float2bfloat16(f.z); t.a[3] = __float2bfloat16(f.w);
                        *(uint2*)&Al[arow_l * VWS + colf] = t.u;
                    }
                } else {
                    const bf16* ap = (const bf16*)A + (size_t)grow * 256;
                    #pragma unroll
                    for (int j = 0; j < 8; j++) {
                        int cole = j * 32 + asub * 8;    // quad covers 64B
                        *(uint4*)&Al[arow_l * VWS + cole] = *(const uint4*)(ap + cole);
                    }
                }
            } else {
                uint4 z = make_uint4(0u, 0u, 0u, 0u);
                #pragma unroll
                for (int j = 0; j < 8; j++)
                    *(uint4*)&Al[arow_l * VWS + j * 32 + asub * 8] = z;
            }
        }
        __syncthreads();                      // A tile ready

        // ---- compute: 8 K-steps x (4 m-frags x 4 n-frags) = 128 MFMAs ----
        f32x4 acc[4][4];
        #pragma unroll
        for (int mi = 0; mi < 4; mi++)
            #pragma unroll
            for (int nt = 0; nt < 4; nt++)
                acc[mi][nt] = (f32x4){0.f, 0.f, 0.f, 0.f};

        #pragma unroll
        for (int ks = 0; ks < 8; ks++) {
            bf16x8 af[4];
            #pragma unroll
            for (int mi = 0; mi < 4; mi++)
                af[mi] = *(const bf16x8*)&Al[(mi * 16 + lm) * VWS + ks * 32 + lq * 8];
            #pragma unroll
            for (int nt = 0; nt < 4; nt++)
                #pragma unroll
                for (int mi = 0; mi < 4; mi++)
                    acc[mi][nt] = __builtin_amdgcn_mfma_f32_16x16x32_bf16(
                                      af[mi], wf[nt][ks], acc[mi][nt], 0, 0, 0);
        }

        // ---- write C tile (bf16) ----
        #pragma unroll
        for (int mi = 0; mi < 4; mi++) {
            #pragma unroll
            for (int r = 0; r < 4; r++) {
                int m = m0 + mi * 16 + lq * 4 + r;
                if (m >= M) continue;
                #pragma unroll
                for (int nt = 0; nt < 4; nt++) {
                    int col = wq + nt * 16 + lm;
                    C[(size_t)m * 256 + col] = __float2bfloat16(acc[mi][nt][r] + bv[nt]);
                }
            }
        }
    }
}

// ---------------------------------------------------------------------------
// stage A tile [32][32] : thread t -> row t>>3, col (t&7)*4  (uint2 / float4)
// ---------------------------------------------------------------------------
__device__ __forceinline__ void stage_a32(bf16* As, const void* A, bool a_bf16,
        int m0, int M, int K, int k0, int tid)
{
    const int row = tid >> 3, col = (tid & 7) * 4;
    const int arow = m0 + row;
    union { bf16 a[4]; uint2 u; } t;
    if (arow < M) {
        size_t base = (size_t)arow * K + k0 + col;
        if (a_bf16) {
            t.u = *(const uint2*)((const bf16*)A + base);
        } else {
            float4 f = *(const float4*)((const float*)A + base);
            t.a[0] = __float2bfloat16(f.x); t.a[1] = __float2bfloat16(f.y);
            t.a[2] = __float2bfloat16(f.z); t.a[3] = __float2bfloat16(f.w);
        }
    } else {
        t.u = make_uint2(0u, 0u);
    }
    *(uint2*)&As[row * SAK + col] = t.u;
}

// ---------------------------------------------------------------------------
// Plain GEMM, tile 32 x 256. grid: (N/256, ceil(M/32)).
// ---------------------------------------------------------------------------
__global__ __launch_bounds__(256) void gemm_a(const void* __restrict__ A, int amode,
        const bf16* __restrict__ Wb, const void* __restrict__ bias,
        void* __restrict__ C, int cmode, int M, int N, int K, int relu,
        const float* __restrict__ flagp)
{
    const bool ef = flagp[0] > 0.5f;
    const bool a_bf16 = (amode == 1) || (amode == 2 && !ef);
    __shared__ __align__(16) bf16 As[32 * SAK];
    __shared__ __align__(16) bf16 Ws[256 * SAK];
    const int tid = threadIdx.x;
    const int m0 = blockIdx.y * 32, n0 = blockIdx.x * 256;
    const int w = tid >> 6, lane = tid & 63, lm = lane & 15, lq = lane >> 4;
    const int wr = w >> 1, wc = w & 1;
    const int srow = tid >> 2, scol = (tid & 3) * 8;

    f32x4 acc[8];
    #pragma unroll
    for (int nt = 0; nt < 8; nt++) acc[nt] = (f32x4){0.f, 0.f, 0.f, 0.f};

    for (int k0 = 0; k0 < K; k0 += 32) {
        stage_a32(As, A, a_bf16, m0, M, K, k0, tid);
        #pragma unroll
        for (int it = 0; it < 4; it++) {
            int rr = it * 64 + srow;
            *(uint4*)&Ws[rr * SAK + scol] =
                *(const uint4*)(Wb + (size_t)(n0 + rr) * K + k0 + scol);
        }
        __syncthreads();

        bf16x8 af = *(const bf16x8*)&As[(wr * 16 + lm) * SAK + lq * 8];
        #pragma unroll
        for (int nt = 0; nt < 8; nt++) {
            bf16x8 bfr = *(const bf16x8*)&Ws[(wc * 128 + nt * 16 + lm) * SAK + lq * 8];
            acc[nt] = __builtin_amdgcn_mfma_f32_16x16x32_bf16(af, bfr, acc[nt], 0, 0, 0);
        }
        __syncthreads();
    }

    #pragma unroll
    for (int nt = 0; nt < 8; nt++) {
        int n = n0 + wc * 128 + nt * 16 + lm;
        float bv = ldv(bias, n, 2, ef);
        #pragma unroll
        for (int r = 0; r < 4; r++) {
            int m = m0 + wr * 16 + lq * 4 + r;
            if (m >= M) continue;
            float v = acc[nt][r] + bv;
            if (relu) v = fmaxf(v, 0.f);
            size_t ci = (size_t)m * N + n;
            if (cmode == 0) ((float*)C)[ci] = v;
            else            ((bf16*)C)[ci] = __float2bfloat16(v);
        }
    }
}

// ---------------------------------------------------------------------------
// Fused GEMM (N=256) + bias + residual + LayerNorm. Tile 32 x 256.
// ---------------------------------------------------------------------------
__global__ __launch_bounds__(256) void gemm_ln(const bf16* __restrict__ A,
        const bf16* __restrict__ Wb, const void* __restrict__ bias,
        const float* __restrict__ res, const void* __restrict__ gw,
        const void* __restrict__ bw, float* __restrict__ out32,
        bf16* __restrict__ outbf, void* __restrict__ dout, size_t obase,
        const void* __restrict__ qp, int M, int K,
        const float* __restrict__ flagp)
{
    const bool ef = flagp[0] > 0.5f;
    __shared__ __align__(16) bf16 As[32 * SAK];
    __shared__ __align__(16) bf16 Ws[256 * SAK];
    const int tid = threadIdx.x;
    const int m0 = blockIdx.y * 32;
    const int w = tid >> 6, lane = tid & 63, lm = lane & 15, lq = lane >> 4;
    const int wr = w >> 1, wc = w & 1;
    const int srow = tid >> 2, scol = (tid & 3) * 8;

    f32x4 acc[8];
    #pragma unroll
    for (int nt = 0; nt < 8; nt++) acc[nt] = (f32x4){0.f, 0.f, 0.f, 0.f};

    for (int k0 = 0; k0 < K; k0 += 32) {
        stage_a32(As, A, true, m0, M, K, k0, tid);
        #pragma unroll
        for (int it = 0; it < 4; it++) {
            int rr = it * 64 + srow;
            *(uint4*)&Ws[rr * SAK + scol] =
                *(const uint4*)(Wb + (size_t)rr * K + k0 + scol);
        }
        __syncthreads();

        bf16x8 af = *(const bf16x8*)&As[(wr * 16 + lm) * SAK + lq * 8];
        #pragma unroll
        for (int nt = 0; nt < 8; nt++) {
            bf16x8 bfr = *(const bf16x8*)&Ws[(wc * 128 + nt * 16 + lm) * SAK + lq * 8];
            acc[nt] = __builtin_amdgcn_mfma_f32_16x16x32_bf16(af, bfr, acc[nt], 0, 0, 0);
        }
        __syncthreads();
    }

    float bias_c[8], gcol[8], bcol[8];
    #pragma unroll
    for (int nt = 0; nt < 8; nt++) {
        int col = wc * 128 + nt * 16 + lm;
        bias_c[nt] = ldv(bias, col, 2, ef);
        gcol[nt]   = ldv(gw,   col, 2, ef);
        bcol[nt]   = ldv(bw,   col, 2, ef);
    }
    #pragma unroll
    for (int r = 0; r < 4; r++) {
        int row = m0 + wr * 16 + lq * 4 + r;
        bool vr_ = row < M;
        #pragma unroll
        for (int nt = 0; nt < 8; nt++) {
            int col = wc * 128 + nt * 16 + lm;
            float rv = vr_ ? res[(size_t)row * DM + col] : 0.f;
            acc[nt][r] += bias_c[nt] + rv;
        }
    }

    float* red = (float*)As;
    float mu[4], rstd[4];
    #pragma unroll
    for (int r = 0; r < 4; r++) {
        float s = 0.f;
        #pragma unroll
        for (int nt = 0; nt < 8; nt++) s += acc[nt][r];
        s += __shfl_xor(s, 1, 64); s += __shfl_xor(s, 2, 64);
        s += __shfl_xor(s, 4, 64); s += __shfl_xor(s, 8, 64);
        if (lm == 0) red[(wr * 16 + lq * 4 + r) * 2 + wc] = s;
    }
    __syncthreads();
    #pragma unroll
    for (int r = 0; r < 4; r++) {
        int rl = wr * 16 + lq * 4 + r;
        mu[r] = (red[rl * 2] + red[rl * 2 + 1]) * (1.f / DM);
    }
    #pragma unroll
    for (int r = 0; r < 4; r++) {
        float q = 0.f;
        #pragma unroll
        for (int nt = 0; nt < 8; nt++) {
            float d = acc[nt][r] - mu[r];
            q += d * d;
        }
        q += __shfl_xor(q, 1, 64); q += __shfl_xor(q, 2, 64);
        q += __shfl_xor(q, 4, 64); q += __shfl_xor(q, 8, 64);
        if (lm == 0) red[64 + (wr * 16 + lq * 4 + r) * 2 + wc] = q;
    }
    __syncthreads();
    #pragma unroll
    for (int r = 0; r < 4; r++) {
        int rl = wr * 16 + lq * 4 + r;
        float var = (red[64 + rl * 2] + red[64 + rl * 2 + 1]) * (1.f / DM);
        rstd[r] = rsqrtf(var + LN_EPS);
    }

    #pragma unroll
    for (int r = 0; r < 4; r++) {
        int row = m0 + wr * 16 + lq * 4 + r;
        if (row >= M) continue;
        size_t rbase = (size_t)row * DM;
        #pragma unroll
        for (int nt = 0; nt < 8; nt++) {
            int col = wc * 128 + nt * 16 + lm;
            float o = (acc[nt][r] - mu[r]) * rstd[r] * gcol[nt] + bcol[nt];
            if (dout) {
                if (ef) ((float*)dout)[obase + rbase + col] = o;
                else    ((bf16*)dout)[obase + rbase + col] = __float2bfloat16(o);
            }
            float o2 = o + (qp ? ldv(qp, rbase + col, 2, ef) : 0.f);
            out32[rbase + col] = o2;
            outbf[rbase + col] = __float2bfloat16(o2);
        }
    }
}

// ---------------------------------------------------------------------------
// Fused sampling-offset + attention-weight GEMM: W = concat(so_w, aw_w) rows
// (N=384). Tile 32 x 128; grid (3, ceil(M/32)).
// ---------------------------------------------------------------------------
__global__ __launch_bounds__(256) void gemm_soaw(const bf16* __restrict__ A,
        const bf16* __restrict__ Wb, const void* __restrict__ b1,
        const void* __restrict__ b2, float* __restrict__ C1,
        float* __restrict__ C2, int M, const float* __restrict__ flagp)
{
    const bool ef = flagp[0] > 0.5f;
    const int K = DM;
    __shared__ __align__(16) bf16 As[32 * SAK];
    __shared__ __align__(16) bf16 Ws[128 * SAK];
    const int tid = threadIdx.x;
    const int m0 = blockIdx.y * 32, n0 = blockIdx.x * 128;
    const int w = tid >> 6, lane = tid & 63, lm = lane & 15, lq = lane >> 4;
    const int wr = w >> 1, wc = w & 1;
    const int srow = tid >> 2, scol = (tid & 3) * 8;

    f32x4 acc[4];
    #pragma unroll
    for (int nt = 0; nt < 4; nt++) acc[nt] = (f32x4){0.f, 0.f, 0.f, 0.f};

    for (int k0 = 0; k0 < K; k0 += 32) {
        stage_a32(As, A, true, m0, M, K, k0, tid);
        #pragma unroll
        for (int it = 0; it < 2; it++) {
            int rr = it * 64 + srow;
            *(uint4*)&Ws[rr * SAK + scol] =
                *(const uint4*)(Wb + (size_t)(n0 + rr) * K + k0 + scol);
        }
        __syncthreads();

        bf16x8 af = *(const bf16x8*)&As[(wr * 16 + lm) * SAK + lq * 8];
        #pragma unroll
        for (int nt = 0; nt < 4; nt++) {
            bf16x8 bfr = *(const bf16x8*)&Ws[(wc * 64 + nt * 16 + lm) * SAK + lq * 8];
            acc[nt] = __builtin_amdgcn_mfma_f32_16x16x32_bf16(af, bfr, acc[nt], 0, 0, 0);
        }
        __syncthreads();
    }

    float* Cd; const void* bsrc; int nst, c0;
    if (n0 < 256) { Cd = C1; bsrc = b1; nst = 256; c0 = n0; }
    else          { Cd = C2; bsrc = b2; nst = 128; c0 = n0 - 256; }

    #pragma unroll
    for (int nt = 0; nt < 4; nt++) {
        int cl = wc * 64 + nt * 16 + lm;
        float bv = ldv(bsrc, c0 + cl, 2, ef);
        #pragma unroll
        for (int r = 0; r < 4; r++) {
            int m = m0 + wr * 16 + lq * 4 + r;
            if (m >= M) continue;
            Cd[(size_t)m * nst + c0 + cl] = acc[nt][r] + bv;
        }
    }
}

// ---------------------------------------------------------------------------
__global__ __launch_bounds__(256) void add_qpos(const void* __restrict__ a, int amode,
        const void* __restrict__ qp, float* __restrict__ o, bf16* __restrict__ ob,
        const float* __restrict__ flagp)
{
    const bool ef = flagp[0] > 0.5f;
    int i = blockIdx.x * 256 + threadIdx.x;
    float v = ldv(a, i, amode, ef) + ldv(qp, i, 2, ef);
    o[i]  = v;
    ob[i] = __float2bfloat16(v);
}

// ---------------------------------------------------------------------------
// MFMA flash MHA. grid (15 qtiles, 8 h, 8 b), 256 thr = 4 waves.
// P stored row-major [q][k] (stride PSK=88): the per-mt 4 sv values are
// consecutive k -> one ds_write_b64 each (4 total), and the PV fragment is
// one contiguous ds_read_b128 per ks (2 total) — replaces 16 scalar b16
// writes + 16 scalar b16 reads per wave per k-tile.
// ---------------------------------------------------------------------------
__global__ __launch_bounds__(256) void mha_mfma(const bf16* __restrict__ qkv,
        bf16* __restrict__ out)
{
    const int qt = blockIdx.x, h = blockIdx.y, b = blockIdx.z;
    const int q0 = qt * 64;
    const int tid = threadIdx.x;
    const int w = tid >> 6, lane = tid & 63;
    const int lm = lane & 15, lq = lane >> 4;
    const int srow = tid >> 2, sc = (tid & 3) * 8;

    __shared__ __align__(16) bf16 Qs[64][SAK];
    __shared__ __align__(16) bf16 Ks[64][SAK];
    __shared__ __align__(16) bf16 Vt[32][66];
    __shared__ __align__(16) bf16 Ps[64][PSK];

    const bf16* base = qkv + (size_t)b * NQ * 768;

    {
        bf16 tmp[8];
        if (q0 + srow < NQ) {
            uint4 u = *(const uint4*)(base + (size_t)(q0 + srow) * 768 + h * DHEAD + sc);
            float t[8]; unpack8(u, t);
            #pragma unroll
            for (int i = 0; i < 8; i++) tmp[i] = __float2bfloat16(t[i] * ATT_SCALE);
        } else {
            #pragma unroll
            for (int i = 0; i < 8; i++) tmp[i] = __float2bfloat16(0.f);
        }
        *(uint4*)&Qs[srow][sc] = *(const uint4*)tmp;
    }
    __syncthreads();
    const bf16x8 qf = *(const bf16x8*)&Qs[w * 16 + lm][lq * 8];

    f32x4 O[2] = {{0.f,0.f,0.f,0.f},{0.f,0.f,0.f,0.f}};
    float mrow = -1e30f, lrow = 0.f;

    for (int k0 = 0; k0 < NQ; k0 += 64) {
        __syncthreads();
        {
            uint4 uk = {0u,0u,0u,0u}, uv = {0u,0u,0u,0u};
            if (k0 + srow < NQ) {
                const bf16* rp = base + (size_t)(k0 + srow) * 768 + h * DHEAD + sc;
                uk = *(const uint4*)(rp + 256);
                uv = *(const uint4*)(rp + 512);
            }
            *(uint4*)&Ks[srow][sc] = uk;
            const bf16* vv = (const bf16*)&uv;
            #pragma unroll
            for (int i = 0; i < 8; i++) Vt[sc + i][srow] = vv[i];
        }
        __syncthreads();

        float sv[16];
        #pragma unroll
        for (int mt = 0; mt < 4; mt++) {
            bf16x8 kf = *(const bf16x8*)&Ks[mt * 16 + lm][lq * 8];
            f32x4 d = __builtin_amdgcn_mfma_f32_16x16x32_bf16(kf, qf,
                        (f32x4){0.f,0.f,0.f,0.f}, 0, 0, 0);
            sv[mt*4+0] = d[0]; sv[mt*4+1] = d[1]; sv[mt*4+2] = d[2]; sv[mt*4+3] = d[3];
        }
        #pragma unroll
        for (int mt = 0; mt < 4; mt++)
            #pragma unroll
            for (int r = 0; r < 4; r++)
                if (k0 + mt * 16 + lq * 4 + r >= NQ) sv[mt*4+r] = -1e30f;

        float tmax = sv[0];
        #pragma unroll
        for (int j = 1; j < 16; j++) tmax = fmaxf(tmax, sv[j]);
        tmax = fmaxf(tmax, __shfl_xor(tmax, 16, 64));
        tmax = fmaxf(tmax, __shfl_xor(tmax, 32, 64));
        float mnew = fmaxf(mrow, tmax);
        float alpha = __expf(mrow - mnew);
        mrow = mnew;
        float psum = 0.f;
        #pragma unroll
        for (int j = 0; j < 16; j++) {
            float p = __expf(sv[j] - mnew);
            sv[j] = p; psum += p;
        }
        psum += __shfl_xor(psum, 16, 64);
        psum += __shfl_xor(psum, 32, 64);
        lrow = lrow * alpha + psum;

        // ---- write P row-major: P[q][k], 4x ds_write_b64 ----
        #pragma unroll
        for (int mt = 0; mt < 4; mt++) {
            union { bf16 a[4]; uint2 u; } pw;
            #pragma unroll
            for (int r = 0; r < 4; r++) pw.a[r] = __float2bfloat16(sv[mt*4+r]);
            *(uint2*)&Ps[w * 16 + lm][mt * 16 + lq * 4] = pw.u;
        }

        #pragma unroll
        for (int mt = 0; mt < 2; mt++)
            #pragma unroll
            for (int r = 0; r < 4; r++) O[mt][r] *= alpha;
        #pragma unroll
        for (int ks = 0; ks < 2; ks++) {
            bf16x8 pf = *(const bf16x8*)&Ps[w * 16 + lm][ks * 32 + lq * 8];
            #pragma unroll
            for (int mt = 0; mt < 2; mt++) {
                bf16x8 vf = *(const bf16x8*)&Vt[mt * 16 + lm][ks * 32 + lq * 8];
                O[mt] = __builtin_amdgcn_mfma_f32_16x16x32_bf16(vf, pf, O[mt], 0, 0, 0);
            }
        }
    }

    int q = q0 + w * 16 + lm;
    if (q < NQ) {
        float invl = 1.f / lrow;
        bf16* op = out + ((size_t)(b * NQ + q)) * DM + h * DHEAD;
        #pragma unroll
        for (int mt = 0; mt < 2; mt++)
            #pragma unroll
            for (int r = 0; r < 4; r++)
                op[mt * 16 + lq * 4 + r] = __float2bfloat16(O[mt][r] * invl);
    }
}

// ---------------------------------------------------------------------------
// MSDA sampling, 8 queries/block. Thread = (query qi, head h, chan-group cg).
// ---------------------------------------------------------------------------
__global__ __launch_bounds__(256) void msda_sample8(const bf16* __restrict__ value,
        const float* __restrict__ off, const float* __restrict__ aw,
        const void* __restrict__ refp, const void* __restrict__ vr,
        bf16* __restrict__ out, const float* __restrict__ flagp)
{
    const bool ef = flagp[0] > 0.5f;
    const int tid = threadIdx.x;
    const int bq0 = blockIdx.x * 8;

    __shared__ float sOff[8][256];
    __shared__ float sAw[8][128];
    __shared__ float sref[8][2];
    __shared__ float svrq[8][8];

    {
        const float* osrc = off + (size_t)bq0 * 256;
        #pragma unroll
        for (int i = 0; i < 2; i++) {
            int e = i * 1024 + tid * 4;
            *(float4*)&sOff[e >> 8][e & 255] = *(const float4*)(osrc + e);
        }
        int e2 = tid * 4;
        *(float4*)&sAw[e2 >> 7][e2 & 127] = *(const float4*)(aw + (size_t)bq0 * 128 + e2);
    }
    if (tid < 16) sref[tid >> 1][tid & 1] = ldv(refp, (size_t)(bq0 + (tid >> 1)) * 2 + (tid & 1), 2, ef);
    if (tid < 64) {
        int qi = tid >> 3, j = tid & 7;
        int b = (bq0 + qi) / NQ;
        svrq[qi][j] = ldv(vr, b * 8 + j, 2, ef);
    }
    __syncthreads();

    if (tid < 64) {
        int qi = tid >> 3, h = tid & 7;
        float* p = &sAw[qi][h * 16];
        float mx = -1e30f;
        #pragma unroll
        for (int j = 0; j < 16; j++) mx = fmaxf(mx, p[j]);
        float s = 0.f;
        #pragma unroll
        for (int j = 0; j < 16; j++) { float e = __expf(p[j] - mx); p[j] = e; s += e; }
        float inv = 1.f / s;
        #pragma unroll
        for (int j = 0; j < 16; j++) p[j] *= inv;
    }
    __syncthreads();

    const int qi = tid >> 5, sub = tid & 31;
    const int h = sub >> 2, cg = sub & 3;
    const int bq = bq0 + qi;
    const int b = bq / NQ;
    const bf16* vb = value + (size_t)b * NS * DM + h * DHEAD + cg * 8;

    float acc[8];
    #pragma unroll
    for (int j = 0; j < 8; j++) acc[j] = 0.f;

    const int HS[4] = {100, 50, 25, 13};
    const int ST[4] = {0, 10000, 12500, 13125};
    #pragma unroll
    for (int lvl = 0; lvl < 4; lvl++) {
        const int W_ = HS[lvl], H_ = HS[lvl], st = ST[lvl];
        float rx = sref[qi][0] * svrq[qi][lvl * 2 + 0] * (float)W_;
        float ry = sref[qi][1] * svrq[qi][lvl * 2 + 1] * (float)H_;
        #pragma unroll
        for (int p = 0; p < 4; p++) {
            int oi = h * 32 + lvl * 8 + p * 2;
            float x = fminf(fmaxf(rx + sOff[qi][oi]     - 0.5f, -4.f), (float)W_ + 4.f);
            float y = fminf(fmaxf(ry + sOff[qi][oi + 1] - 0.5f, -4.f), (float)H_ + 4.f);
            float x0f = floorf(x), y0f = floorf(y);
            float wx = x - x0f, wy = y - y0f;
            int x0 = (int)x0f, y0 = (int)y0f;
            int x1i = x0 + 1, y1i = y0 + 1;
            bool vx0 = (x0 >= 0) && (x0 < W_), vx1 = (x1i >= 0) && (x1i < W_);
            bool vy0 = (y0 >= 0) && (y0 < H_), vy1 = (y1i >= 0) && (y1i < H_);
            float g[8];
            #pragma unroll
            for (int j = 0; j < 8; j++) g[j] = 0.f;
            float t[8];
            if (vy0) {
                int rowo = (st + y0 * W_) * DM;
                if (vx0) {
                    uint4 u = *(const uint4*)(vb + rowo + x0 * DM);
                    unpack8(u, t);
                    float wgt = (1.f - wx) * (1.f - wy);
                    #pragma unroll
                    for (int j = 0; j < 8; j++) g[j] += wgt * t[j];
                }
                if (vx1) {
                    uint4 u = *(const uint4*)(vb + rowo + x1i * DM);
                    unpack8(u, t);
                    float wgt = wx * (1.f - wy);
                    #pragma unroll
                    for (int j = 0; j < 8; j++) g[j] += wgt * t[j];
                }
            }
            if (vy1) {
                int rowo = (st + y1i * W_) * DM;
                if (vx0) {
                    uint4 u = *(const uint4*)(vb + rowo + x0 * DM);
                    unpack8(u, t);
                    float wgt = (1.f - wx) * wy;
                    #pragma unroll
                    for (int j = 0; j < 8; j++) g[j] += wgt * t[j];
                }
                if (vx1) {
                    uint4 u = *(const uint4*)(vb + rowo + x1i * DM);
                    unpack8(u, t);
                    float wgt = wx * wy;
                    #pragma unroll
                    for (int j = 0; j < 8; j++) g[j] += wgt * t[j];
                }
            }
            float a = sAw[qi][h * 16 + lvl * 4 + p];
            #pragma unroll
            for (int j = 0; j < 8; j++) acc[j] += a * g[j];
        }
    }

    union { bf16 t[8]; uint4 u; } pk;
    #pragma unroll
    for (int j = 0; j < 8; j++) pk.t[j] = __float2bfloat16(acc[j]);
    *(uint4*)(out + (size_t)bq * DM + h * DHEAD + cg * 8) = pk.u;
}

// ---------------------------------------------------------------------------
__global__ __launch_bounds__(256) void copy_refs(const void* __restrict__ refp,
        void* __restrict__ out, const float* __restrict__ flagp)
{
    const bool ef = flagp[0] > 0.5f;
    int i = blockIdx.x * 256 + threadIdx.x;
    if (i >= NLAY * BQ * 2) return;
    float v = ldv(refp, i % (BQ * 2), 2, ef);
    size_t oi = (size_t)NLAY * BQ * DM + i;
    if (ef) ((float*)out)[oi] = v;
    else    ((bf16*)out)[oi] = __float2bfloat16(v);
}

// ---------------------------------------------------------------------------
extern "C" void kernel_launch(void* const* d_in, const int* in_sizes, int n_in,
                              void* d_out, int out_size, void* d_ws, size_t ws_size,
                              hipStream_t stream)
{
    const void* tgt     = d_in[0];
    const void* refp    = d_in[1];
    const void* memory  = d_in[2];
    const void* vr      = d_in[5];
    const void* qp      = d_in[6];
    const void* sa_in_w = d_in[7];
    const void* sa_in_b = d_in[8];
    const void* sa_out_w= d_in[9];
    const void* sa_out_b= d_in[10];
    const void* n1_g    = d_in[11];
    const void* n1_b    = d_in[12];
    const void* n2_g    = d_in[13];
    const void* n2_b    = d_in[14];
    const void* n3_g    = d_in[15];
    const void* n3_b    = d_in[16];
    const void* vp_w    = d_in[17];
    const void* vp_b    = d_in[18];
    const void* so_w    = d_in[19];
    const void* so_b    = d_in[20];
    const void* aw_w    = d_in[21];
    const void* aw_b    = d_in[22];
    const void* op_w    = d_in[23];
    const void* op_b    = d_in[24];
    const void* ff1_w   = d_in[25];
    const void* ff1_b   = d_in[26];
    const void* ff2_w   = d_in[27];
    const void* ff2_b   = d_in[28];

    // ---- workspace layout ----
    char* w = (char*)d_ws;
    float* flagp  = (float*)w;  w += 256;
    bf16*  value  = (bf16*)w;   w += (size_t)NB * NS * DM * 2;   // 54.45 MB
    float* outbuf = (float*)w;  w += (size_t)BQ * DM * 4;
    float* x1samp = (float*)w;  w += (size_t)BQ * DM * 4;
    bf16*  bigb   = (bf16*)w;   w += (size_t)BQ * NFF * 2;       // qkv / ffn hidden
    float* attoff = (float*)w;  w += (size_t)BQ * DM * 4;        // sampling offsets
    float* awb    = (float*)w;  w += (size_t)BQ * 128 * 4;       // aw logits
    bf16*  abuf   = (bf16*)w;   w += (size_t)BQ * DM * 2;        // x1/mha/msda bf16
    bf16*  outbf  = (bf16*)w;   w += (size_t)BQ * DM * 2;        // ln bf16 dup
    // pre-converted bf16 weights
    bf16* wb_sa_in = (bf16*)w;  w += (size_t)768 * 256 * 2;
    bf16* wb_sa_out= (bf16*)w;  w += (size_t)256 * 256 * 2;
    bf16* wb_soaw  = (bf16*)w;  w += (size_t)384 * 256 * 2;      // so(256) ++ aw(128)
    bf16* wb_op    = (bf16*)w;  w += (size_t)256 * 256 * 2;
    bf16* wb_ff1   = (bf16*)w;  w += (size_t)NFF * 256 * 2;
    bf16* wb_ff2   = (bf16*)w;  w += (size_t)256 * NFF * 2;
    bf16* wb_vp    = (bf16*)w;  w += (size_t)256 * 256 * 2;

    const int gy = (BQ + 31) / 32;      // 225
    const int MV = NB * NS;             // 106352

    // 0) detect external dtype, pre-convert weights to bf16
    detect_dtype<<<1, 256, 0, stream>>>(tgt, flagp);
    convert_w<<< 96, 256, 0, stream>>>(sa_in_w,  wb_sa_in,  flagp);
    convert_w<<< 32, 256, 0, stream>>>(sa_out_w, wb_sa_out, flagp);
    convert_w<<< 32, 256, 0, stream>>>(so_w,     wb_soaw,   flagp);
    convert_w<<< 16, 256, 0, stream>>>(aw_w,     wb_soaw + 256 * 256, flagp);
    convert_w<<< 32, 256, 0, stream>>>(op_w,     wb_op,     flagp);
    convert_w<<<128, 256, 0, stream>>>(ff1_w,    wb_ff1,    flagp);
    convert_w<<<128, 256, 0, stream>>>(ff2_w,    wb_ff2,    flagp);
    convert_w<<< 32, 256, 0, stream>>>(vp_w,     wb_vp,     flagp);

    // 1) value projection: W-in-registers GEMM (round-7 proven config)
    gemm_vp<<<512, 256, 0, stream>>>(memory, wb_vp, vp_b, value, MV, flagp);

    // 2) inter_refs output
    copy_refs<<<(NLAY * BQ * 2 + 255) / 256, 256, 0, stream>>>(refp, d_out, flagp);

    // 3) x1 = tgt + query_pos (layer 0 only; later layers fused into ff2 LN)
    add_qpos<<<BQ * DM / 256, 256, 0, stream>>>(tgt, 2, qp, x1samp, abuf, flagp);

    for (int l = 0; l < NLAY; l++) {
        // self-attention
        gemm_a<<<dim3(768/256, gy), 256, 0, stream>>>(
            abuf, 1, wb_sa_in, sa_in_b, bigb, 1, BQ, 768, DM, 0, flagp);
        mha_mfma<<<dim3(15, NHEADS, NB), 256, 0, stream>>>(bigb, abuf);
        gemm_ln<<<dim3(1, gy), 256, 0, stream>>>(
            abuf, wb_sa_out, sa_out_b, x1samp, n1_g, n1_b,
            outbuf, outbf, nullptr, 0, nullptr, BQ, DM, flagp);

        // MSDA: fused so+aw GEMM, 8-query sampling w/ inline softmax, op+LN2
        gemm_soaw<<<dim3(3, gy), 256, 0, stream>>>(
            outbf, wb_soaw, so_b, aw_b, attoff, awb, BQ, flagp);
        msda_sample8<<<BQ / 8, 256, 0, stream>>>(value, attoff, awb, refp, vr, abuf, flagp);
        gemm_ln<<<dim3(1, gy), 256, 0, stream>>>(
            abuf, wb_op, op_b, outbuf, n2_g, n2_b,
            outbuf, outbf, nullptr, 0, nullptr, BQ, DM, flagp);

        // FFN: ff1 (relu, bf16 hidden), ff2 + LN3 + d_out slice + next x1(+qp)
        gemm_a<<<dim3(NFF/256, gy), 256, 0, stream>>>(
            outbf, 1, wb_ff1, ff1_b, bigb, 1, BQ, NFF, DM, 1, flagp);
        gemm_ln<<<dim3(1, gy), 256, 0, stream>>>(
            bigb, wb_ff2, ff2_b, outbuf, n3_g, n3_b,
            x1samp, abuf, d_out, (size_t)l * BQ * DM, qp, BQ, NFF, flagp);
    }
}